// Round 15
// baseline (134.719 us; speedup 1.0000x reference)
//
#include <hip/hip_runtime.h>
#include <cstddef>

// LMMD loss, round 28 = round 27 (111.3-111.5 us best) with k3 staging
// 3-buffer (48 KB) -> 2-buffer ping-pong (32 KB): LDS 52->35.8 KB lifts the
// occupancy cap 3 -> 4 blocks/CU (launch_bounds (256,4); 84 VGPR < 128
// budget, no spill expected). Cost: vmcnt(0) drains at two interior
// barriers (counted-vmcnt was worth only ~1.7 us in r19); gain: +33%
// resident waves on a kernel whose stall is pure latency exposure
// (21% occupancy, no pipe >35%). Single-variable A/B vs r27.
// Everything else byte-identical to r27.
// loss = (1/n_idx) * sum_{p<=q} f_pq * w_pq * K(p,q),  f=2 off-diag, 1 diag
// Features: fp8 e4m3 MFMA (verified round 12: absmax 2.4e-4 < 4.9e-4).

#define B 4096
#define D 256
#define C 31
#define N2 8192
#define NTILE 64                       // 128-row tiles over 2B rows
#define NBLK (NTILE * (NTILE + 1) / 2) // 2080

typedef __attribute__((ext_vector_type(8))) short bf16x8;
typedef __attribute__((ext_vector_type(4))) float f32x4;

struct WS {
  float inv_n_idx;
  float inv_d4;
  float pSumsq[256];                  // per-block sum(x^2) partials
  unsigned pTpres[128];               // per-target-block argmax ballot mask
  alignas(16) float pMsum[256 * 256]; // [blk][col] column-sum partials
  alignas(16) int pScnt[128 * 32];    // [src blk][class] label counts
  alignas(16) float pTcnt[128 * 32];  // [tgt blk][class] t_label col sums
  float sq[N2];
  int slab[N2];
  float sdv[N2];
  alignas(16) unsigned char Thi8[(size_t)N2 * D];   // fp8 e4m3 (rotated)
  alignas(16) unsigned short vhi[(size_t)N2 * 32];  // bf16 v rows (tgt only)
  alignas(16) double part[NBLK];                    // per-block partial loss
};

static __device__ __forceinline__ unsigned short f2bf(float f) {
  unsigned int u = __float_as_uint(f);
  return (unsigned short)((u + 0x7fffu + ((u >> 16) & 1u)) >> 16);  // RNE
}
static __device__ __forceinline__ float bf2f(unsigned short s) {
  return __uint_as_float(((unsigned int)s) << 16);
}
static __device__ __forceinline__ float exp2_hw(float x) {
  float r;
  asm("v_exp_f32 %0, %1" : "=v"(r) : "v"(x));  // HW exp = 2^x
  return r;
}

#define GLD16(gsrc, ldst)                                                     \
  __builtin_amdgcn_global_load_lds(                                           \
      (const __attribute__((address_space(1))) void*)(gsrc),                  \
      (__attribute__((address_space(3))) void*)(ldst), 16, 0, 0)

// Prep + stats: fp8 feature pack, row sq, per-block partial stats.
// Blocks 0-127 cover source rows, 128-255 target rows (32 rows each).
__global__ __launch_bounds__(256) void kPrep(const float* __restrict__ src,
                                             const float* __restrict__ tgt,
                                             const int* __restrict__ s_label,
                                             const float* __restrict__ t_label,
                                             WS* __restrict__ ws) {
  int tid = threadIdx.x, w = tid >> 6, lane = tid & 63;
  int blk = blockIdx.x;
  int r0 = blk * 32;
  bool is_src = (r0 < B);  // whole block is one side (B % 32 == 0)
  __shared__ float rsq[32];
  __shared__ float colp[4][256];
  __shared__ int ls[32];
  __shared__ float lt[8][32];  // per-group partial class sums (target blocks)
  __shared__ int lpres[32];
  if (tid < 32) { ls[tid] = 0; lpres[tid] = 0; }

  const float* basep =
      is_src ? src + (size_t)r0 * D : tgt + (size_t)(r0 - B) * D;

  // ---- batched loads: 8 independent float4 loads in flight per thread ----
  float4 xv[8];
#pragma unroll
  for (int i = 0; i < 8; ++i)
    xv[i] = *(const float4*)(basep + (size_t)(w * 8 + i) * D + lane * 4);

  float ca0 = 0.f, ca1 = 0.f, ca2 = 0.f, ca3 = 0.f;
  // fp8 store position pieces: sub-row sc (64 B), granule gl (8 B), half hf
  int sc = lane >> 4, gl = (lane >> 1) & 7, hf = lane & 1;
#pragma unroll
  for (int i = 0; i < 8; ++i) {
    int rr = w * 8 + i;
    int p = r0 + rr;
    float4 x = xv[i];
    // fp8 e4m3 pack: byte0=x.x .. byte3=x.w (HW cvt)
    unsigned int pk = __builtin_amdgcn_cvt_pk_fp8_f32(x.x, x.y, 0, false);
    pk = __builtin_amdgcn_cvt_pk_fp8_f32(x.z, x.w, pk, true);
    // granule rotation keyed by row: r(p)=p+(p>>1) -> conflict-free b64
    // phases on the read side (all 32 banks hit once per 16-lane phase)
    int gp = (gl + p + (p >> 1)) & 7;
    *(unsigned int*)(&ws->Thi8[(size_t)p * D + sc * 64 + gp * 8 + hf * 4]) = pk;
    ca0 += x.x; ca1 += x.y; ca2 += x.z; ca3 += x.w;
    float s = x.x * x.x + x.y * x.y + x.z * x.z + x.w * x.w;
#pragma unroll
    for (int off = 32; off; off >>= 1) s += __shfl_down(s, off, 64);
    if (lane == 0) rsq[rr] = s;
  }
  colp[w][lane * 4 + 0] = ca0;
  colp[w][lane * 4 + 1] = ca1;
  colp[w][lane * 4 + 2] = ca2;
  colp[w][lane * 4 + 3] = ca3;

  // ---- target-block stats, parallel across all 256 threads ----
  if (!is_src) {
    // class sums: thread (g,c) sums rows {4g..4g+3} of class c
    int g = tid >> 5, c = tid & 31;
    float s = 0.f;
    if (c < C) {
#pragma unroll
      for (int k = 0; k < 4; ++k)
        s += t_label[(size_t)(r0 - B + g * 4 + k) * C + c];
    }
    lt[g][c] = s;
    // argmax: 8 threads per row, strided class scan, first-max combine
    int rr = tid >> 3, j = tid & 7;
    float best = -1e30f;
    int barg = 0;
    for (int c2 = j; c2 < C; c2 += 8) {
      float x = t_label[(size_t)(r0 - B + rr) * C + c2];
      if (x > best) { best = x; barg = c2; }  // in-thread scan is ascending
    }
#pragma unroll
    for (int m = 1; m < 8; m <<= 1) {
      float ob = __shfl_xor(best, m, 64);
      int oa = __shfl_xor(barg, m, 64);
      if (ob > best || (ob == best && oa < barg)) { best = ob; barg = oa; }
    }
    if (j == 0) lpres[barg] = 1;  // benign race (all writes are 1)
  }
  __syncthreads();

  if (tid < 32) {
    int p = r0 + tid;
    ws->sq[p] = rsq[tid];
    if (is_src) {
      int lb = s_label[p];
      ws->slab[p] = lb;
      atomicAdd(&ls[lb], 1);  // LDS atomic, 32 lanes, cheap
    } else {
      ws->slab[p] = 0;
    }
  }
  // block sum of sq -> per-block float partial (no global atomic)
  if (tid < 64) {
    float ss = (tid < 32) ? rsq[tid] : 0.f;
#pragma unroll
    for (int off = 32; off; off >>= 1) ss += __shfl_down(ss, off, 64);
    if (tid == 0) ws->pSumsq[blk] = ss;
  }
  // column-sum partials -> plain coalesced stores
  ws->pMsum[blk * 256 + tid] =
      colp[0][tid] + colp[1][tid] + colp[2][tid] + colp[3][tid];
  __syncthreads();
  if (is_src) {
    if (tid < 32) ws->pScnt[blk * 32 + tid] = ls[tid];
  } else {
    if (tid < 32) {
      float s = 0.f;
#pragma unroll
      for (int g = 0; g < 8; ++g) s += lt[g][tid];
      ws->pTcnt[(blk - 128) * 32 + tid] = s;
    }
    if (tid < 64) {  // ballot needs full wave 0
      int bit = (tid < 32) ? lpres[tid] : 0;
      unsigned long long bal = __ballot(bit != 0);
      if (tid == 0) ws->pTpres[blk - 128] = (unsigned)bal;
    }
  }
}

// Finalize: reduce partials -> divisors (redundant per block), inv_n_idx +
// inv_d4 (block 0), sdv all rows + vhi for target rows.
// 32 blocks x 256 threads = one row per thread.
__global__ __launch_bounds__(256) void kFin(const float* __restrict__ t_label,
                                            WS* __restrict__ ws) {
  int tid = threadIdx.x, w = tid >> 6, lane = tid & 63;
  __shared__ float sdiv[32], tdiv[32];
  __shared__ int rs[8][32];
  __shared__ float rt[8][32];
  __shared__ unsigned pm[2];
  __shared__ double dm[4], dsq[4];

  // class partials: thread (g,c) sums 16 blocks' entries
  {
    int g = tid >> 5, c = tid & 31;
    int cs = 0;
    float ts = 0.f;
#pragma unroll
    for (int k = 0; k < 16; ++k) {
      cs += ws->pScnt[(g * 16 + k) * 32 + c];
      ts += ws->pTcnt[(g * 16 + k) * 32 + c];
    }
    rs[g][c] = cs;
    rt[g][c] = ts;
  }
  // t_pres OR-reduce (128 masks, 2 waves)
  if (tid < 128) {
    unsigned m = ws->pTpres[tid];
#pragma unroll
    for (int off = 32; off; off >>= 1) m |= __shfl_down(m, off, 64);
    if ((tid & 63) == 0) pm[tid >> 6] = m;
  }
  __syncthreads();

  if (tid < 64) {
    int m = 0;
    if (tid < 32) {
      int cnt = 0;
      float t = 0.f;
#pragma unroll
      for (int g = 0; g < 8; ++g) { cnt += rs[g][tid]; t += rt[g][tid]; }
      unsigned pres = pm[0] | pm[1];
      m = (tid < C) && (cnt > 0) && ((pres >> tid) & 1u);
      sdiv[tid] = m ? 1.f / (float)cnt : 0.f;
      tdiv[tid] = m ? 1.f / ((t == 0.f) ? 100.f : t) : 0.f;
    }
    unsigned long long bal = __ballot(m);
    if (tid == 0 && blockIdx.x == 0)
      ws->inv_n_idx = 1.f / fmaxf((float)__popcll(bal), 1.f);
  }

  if (blockIdx.x == 0) {
    // Msum + sum_sq reduction -> inv_d4.
    double m = 0.0;
    for (int b2 = 0; b2 < 256; ++b2) m += (double)ws->pMsum[b2 * 256 + tid];
    double msq = m * m;
    double ssq = (double)ws->pSumsq[tid];
#pragma unroll
    for (int off = 32; off; off >>= 1) {
      msq += __shfl_down(msq, off, 64);
      ssq += __shfl_down(ssq, off, 64);
    }
    if (lane == 0) { dm[w] = msq; dsq[w] = ssq; }
    __syncthreads();
    if (tid == 0) {
      double MSQ = dm[0] + dm[1] + dm[2] + dm[3];
      double S = dsq[0] + dsq[1] + dsq[2] + dsq[3];
      double n = (double)N2;
      double sum_l2 = 2.0 * n * S - 2.0 * MSQ;
      double bw = sum_l2 / (n * n - n);
      bw = fmax(bw, 1e-6) * 0.25;  // / KERNEL_MUL^2
      ws->inv_d4 = (float)(1.0 / fmax(bw * 16.0, 1e-6));
    }
  }
  __syncthreads();

  int p = blockIdx.x * 256 + tid;
  if (p < B) {
    ws->sdv[p] = sdiv[ws->slab[p]];
  } else {
    ws->sdv[p] = 0.f;
    const float* r = t_label + (size_t)(p - B) * C;
    float vrow[32];
#pragma unroll
    for (int c = 0; c < 32; ++c) vrow[c] = (c < C) ? -r[c] * tdiv[c] : 0.f;
#pragma unroll
    for (int k = 0; k < 8; ++k) {
      ushort4 vh;
      vh.x = f2bf(vrow[k * 4 + 0]);
      vh.y = f2bf(vrow[k * 4 + 1]);
      vh.z = f2bf(vrow[k * 4 + 2]);
      vh.w = f2bf(vrow[k * 4 + 3]);
      *(ushort4*)(&ws->vhi[(size_t)p * 32 + k * 4]) = vh;
    }
  }
}

// ---- epilogue helpers (forceinlined; KIND 0=SS, 1=ST) ----
// Tables live in LDS: index p-side = local row, q-side = 128 + local row.
// ci2 = inv_d4 * log2(e): z is computed in log2 domain, y = 2^z (v_exp_f32).
template <int KIND, bool DIAG>
static __device__ __forceinline__ float epi_ss_st(
    const f32x4 (&acc)[4][4], float ci2, const float* tSq, const int* tSlab,
    const float* tSdv, const unsigned short* Vsw, int p0, int q0, int wr,
    int wc, int mrow, int quad) {
  float k2 = 2.f * ci2;
  float cq[4], sdq[4];
  int lq[4];
#pragma unroll
  for (int tj = 0; tj < 4; ++tj) {
    int iq = 128 + wc + tj * 16 + mrow;
    cq[tj] = -ci2 * tSq[iq];
    if (KIND == 0) {
      lq[tj] = tSlab[iq];
      sdq[tj] = tSdv[iq];
    }
  }
  float local = 0.f;
#pragma unroll
  for (int ti = 0; ti < 4; ++ti) {
#pragma unroll
    for (int rg = 0; rg < 4; ++rg) {
      int ip = wr + ti * 16 + quad * 4 + rg;
      float cpl = -ci2 * tSq[ip];
      int lp = tSlab[ip];
      float sp = tSdv[ip];
#pragma unroll
      for (int tj = 0; tj < 4; ++tj) {
        float z = fminf(fmaf(k2, acc[ti][tj][rg], cpl + cq[tj]), 0.f);
        float y = exp2_hw(z);
        float kv = y;
        y *= y; kv += y;
        y *= y; kv += y;
        y *= y; kv += y;
        y *= y; kv += y;
        float wv;
        if (KIND == 0) {
          wv = (lp == lq[tj]) ? sp * sdq[tj] : 0.f;
        } else {
          int ql = wc + tj * 16 + mrow;
          wv = sp * bf2f(Vsw[ql * 32 + ((lp + ql) & 31)]);
        }
        if (DIAG) {
          int p = p0 + ip;
          int q = q0 + wc + tj * 16 + mrow;
          float f = (q > p) ? 2.f : ((q == p) ? 1.f : 0.f);
          local = fmaf(wv * f, kv, local);
        } else {
          local = fmaf(wv, kv, local);
        }
      }
    }
  }
  if (!DIAG) local *= 2.f;
  return local;
}

// TT: weight fragment computed inline per (ti,tj) from staged vhi tiles.
template <bool DIAG>
static __device__ __forceinline__ float epi_tt(const f32x4 (&acc)[4][4],
                                               float ci2, const float* tSq,
                                               const unsigned short* SA,
                                               const unsigned short* SB,
                                               int p0, int q0, int wr, int wc,
                                               int mrow, int quad) {
  float k2 = 2.f * ci2;
  float cq[4];
#pragma unroll
  for (int tj = 0; tj < 4; ++tj)
    cq[tj] = -ci2 * tSq[128 + wc + tj * 16 + mrow];
  float cp[16];
#pragma unroll
  for (int ti = 0; ti < 4; ++ti)
#pragma unroll
    for (int rg = 0; rg < 4; ++rg)
      cp[ti * 4 + rg] = -ci2 * tSq[wr + ti * 16 + quad * 4 + rg];
  bf16x8 af[4], bfr[4];
#pragma unroll
  for (int ti = 0; ti < 4; ++ti)
    af[ti] = *(const bf16x8*)(SA + (wr + ti * 16 + mrow) * 32 + quad * 8);
#pragma unroll
  for (int tj = 0; tj < 4; ++tj)
    bfr[tj] = *(const bf16x8*)(SB + (wc + tj * 16 + mrow) * 32 + quad * 8);
  float local = 0.f;
#pragma unroll
  for (int ti = 0; ti < 4; ++ti) {
#pragma unroll
    for (int tj = 0; tj < 4; ++tj) {
      f32x4 wv4 = __builtin_amdgcn_mfma_f32_16x16x32_bf16(
          af[ti], bfr[tj], (f32x4){0.f, 0.f, 0.f, 0.f}, 0, 0, 0);
#pragma unroll
      for (int rg = 0; rg < 4; ++rg) {
        float z = fminf(fmaf(k2, acc[ti][tj][rg], cp[ti * 4 + rg] + cq[tj]), 0.f);
        float y = exp2_hw(z);
        float kv = y;
        y *= y; kv += y;
        y *= y; kv += y;
        y *= y; kv += y;
        y *= y; kv += y;
        if (DIAG) {
          int p = p0 + wr + ti * 16 + quad * 4 + rg;
          int q = q0 + wc + tj * 16 + mrow;
          float f = (q > p) ? 2.f : ((q == p) ? 1.f : 0.f);
          local = fmaf(wv4[rg] * f, kv, local);
        } else {
          local = fmaf(wv4[rg], kv, local);
        }
      }
    }
  }
  if (!DIAG) local *= 2.f;
  return local;
}

// One 64-B chunk = 2 t-steps x 16 fp8 MFMA from buffer fb (A) / fb+8192 (B).
// T5: the MFMA cluster runs at raised wave priority (neutral A/B r25; kept).
static __device__ __forceinline__ void do_chunk(const unsigned char* fb,
                                                f32x4 (&acc)[4][4],
                                                const int (&aAdr)[4],
                                                const int (&bAdr)[4]) {
#pragma unroll
  for (int t = 0; t < 2; ++t) {
    const int x = t << 5;
    long aF[4], bF[4];
#pragma unroll
    for (int ti = 0; ti < 4; ++ti)
      aF[ti] = *(const long*)(fb + (aAdr[ti] ^ x));
#pragma unroll
    for (int tj = 0; tj < 4; ++tj)
      bF[tj] = *(const long*)(fb + 8192 + (bAdr[tj] ^ x));
    __builtin_amdgcn_s_setprio(1);
#pragma unroll
    for (int ti = 0; ti < 4; ++ti)
#pragma unroll
      for (int tj = 0; tj < 4; ++tj)
        acc[ti][tj] = __builtin_amdgcn_mfma_f32_16x16x32_fp8_fp8(
            aF[ti], bF[tj], acc[ti][tj], 0, 0, 0);
    __builtin_amdgcn_s_setprio(0);
  }
}

// counted-vmcnt barrier: wait N outstanding VMEM, raw barrier, memory fence.
#define WBAR(N)                                                               \
  do {                                                                        \
    asm volatile("s_waitcnt vmcnt(" #N ")" ::: "memory");                     \
    __builtin_amdgcn_s_barrier();                                             \
    asm volatile("" ::: "memory");                                            \
  } while (0)

// Merged main kernel: fp8 features, conflict-free rotation, 2-buffer
// ping-pong (35.8 KB LDS -> 4 blocks/CU), fused TT weight GEMM, LDS tables.
__global__ __launch_bounds__(256, 4) void k3_main(WS* __restrict__ ws) {
  int tid = threadIdx.x, w = tid >> 6, lane = tid & 63;
  int lin0 = blockIdx.x;
  int e = (lin0 & 7) * (NBLK / 8) + (lin0 >> 3);
  int b = 0, nb = 484, rem = e;
  while (rem >= nb) { rem -= nb; ++b; nb -= 64; }
  int base = b * 8;
  int bq_, r;
  if (rem < 36) {  // triangular head of the band (bq within band)
    bq_ = 0;
    while ((bq_ + 1) * (bq_ + 2) / 2 <= rem) ++bq_;
    r = rem - (bq_ * (bq_ + 1)) / 2;
  } else {  // full-height 8-row columns
    int t = rem - 36;
    bq_ = 8 + (t >> 3);
    r = t & 7;
  }
  int bp = base + r, bq = base + bq_;
  int p0 = bp * 128, q0 = bq * 128;

  bool is_ss = (bq < 32);
  bool is_tt = (bp >= 32);
  bool is_st = !is_ss && !is_tt;

  // 2 staging buffers (32 KB) + 3 KB tables: chunk c -> buffer c&1.
  __shared__ __align__(16) unsigned char S[2][2][8192];
  __shared__ __align__(16) float tSq[256];
  __shared__ __align__(16) int tSlab[256];
  __shared__ __align__(16) float tSdv[256];
  // post-loop overlays: S[0] free after chunk-2 compute barrier (ST/TT use);
  // S[1] free after chunk-3 compute + final barrier (reduction scratch).
  unsigned short* Vsw = (unsigned short*)&S[0][0][0];  // ST weights (8 KB)
  unsigned short* SA = (unsigned short*)&S[0][0][0];   // TT vhi p-tile
  unsigned short* SB = (unsigned short*)&S[0][1][0];   // TT vhi q-tile
  double* red = (double*)&S[1][0][0];                  // wave partials

  const int wr = (w >> 1) * 64, wc = (w & 1) * 64;
  const int mrow = lane & 15, quad = lane >> 4;
  f32x4 acc[4][4];
#pragma unroll
  for (int i = 0; i < 4; ++i)
#pragma unroll
    for (int j = 0; j < 4; ++j) acc[i][j] = (f32x4){0.f, 0.f, 0.f, 0.f};

  const unsigned char* T8 = ws->Thi8;
  int rA = tid >> 2, cb16 = (tid & 3) * 16, cp8 = (tid & 3) * 8;
  const unsigned char* a_lo = T8 + (size_t)(p0 + rA) * D + cb16;
  const unsigned char* a_hi = a_lo + (size_t)64 * D;
  const unsigned char* b_lo = T8 + (size_t)(q0 + rA) * D + cb16;
  const unsigned char* b_hi = b_lo + (size_t)64 * D;

#define STAGE(bufi, off)                                                      \
  do {                                                                        \
    GLD16(a_lo + (off), &S[bufi][0][w * 1024]);                               \
    GLD16(a_hi + (off), &S[bufi][0][w * 1024 + 4096]);                        \
    GLD16(b_lo + (off), &S[bufi][1][w * 1024]);                               \
    GLD16(b_hi + (off), &S[bufi][1][w * 1024 + 4096]);                        \
  } while (0)

  // hoisted fragment byte-addresses (t=0); t=1 is ^32 (slot ^4)
  int aAdr[4], bAdr[4];
#pragma unroll
  for (int ti = 0; ti < 4; ++ti) {
    int Ra = wr + ti * 16 + mrow;
    aAdr[ti] = Ra * 64 + (((quad + Ra + (Ra >> 1)) & 7) << 3);
    int Rb = wc + ti * 16 + mrow;
    bAdr[ti] = Rb * 64 + (((quad + Rb + (Rb >> 1)) & 7) << 3);
  }

  uint4 stv0 = {0, 0, 0, 0}, stv1 = {0, 0, 0, 0};  // ST early-load regs

  // ---- prologue: c0, c1, tables LAST (so c1 retires before tables) ----
  STAGE(0, 0);
  STAGE(1, 64);
  {
    // epilogue tables: 1024-B GLD16 each, lanes<32 = p-tile, >=32 = q-tile.
    // All 4 waves issue identical loads (same bytes -> benign race) so every
    // wave's outstanding-VMEM count is uniform for the counted waits below.
    int l32 = lane & 31;
    const float* s1 = ((lane < 32) ? ws->sq + p0 : ws->sq + q0) + l32 * 4;
    GLD16(s1, tSq);
    const int* s2 = ((lane < 32) ? ws->slab + p0 : ws->slab + q0) + l32 * 4;
    GLD16(s2, tSlab);
    const float* s3 = ((lane < 32) ? ws->sdv + p0 : ws->sdv + q0) + l32 * 4;
    GLD16(s3, tSdv);
  }
  WBAR(7);  // c0 resident (c1's 4 + tables' 3 still in flight)

  // ---- iter 0: compute c0 ----
  do_chunk(&S[0][0][0], acc, aAdr, bAdr);
  WBAR(3);  // c1 resident (in-order: c0,c1 retired; only tables may fly)

  // ---- iter 1: stage c2 -> S0 (freed), compute c1 ----
  STAGE(0, 128);
  do_chunk(&S[1][0][0], acc, aAdr, bAdr);
  WBAR(0);  // c2 resident (drains tables too; they're needed only post-loop)

  // ---- iter 2: ST early loads; stage c3 -> S1 (freed); compute c2 ----
  if (is_st) {
    const uint4* vsrc = (const uint4*)(ws->vhi + (size_t)(q0 + (tid >> 1)) * 32 +
                                       (tid & 1) * 16);
    stv0 = vsrc[0];
    stv1 = vsrc[1];
  }
  STAGE(1, 192);
  do_chunk(&S[0][0][0], acc, aAdr, bAdr);
  WBAR(0);  // c3 resident (drains ST stv loads too; consumed post-loop)

  // ---- iter 3: TT stages vhi tiles -> S0 (freed); compute c3 ----
  if (is_tt) {
    const unsigned short* gA = ws->vhi + (size_t)(p0 + rA) * 32 + cp8;
    const unsigned short* gB = ws->vhi + (size_t)(q0 + rA) * 32 + cp8;
    GLD16(gA, &S[0][0][w * 1024]);
    GLD16(gA + (size_t)64 * 32, &S[0][0][w * 1024 + 4096]);
    GLD16(gB, &S[0][1][w * 1024]);
    GLD16(gB + (size_t)64 * 32, &S[0][1][w * 1024 + 4096]);
  }
  do_chunk(&S[1][0][0], acc, aAdr, bAdr);

  if (is_st) {
    // ST: write rotate-swizzled bf16 v rows from the early-loaded regs.
    // Vsw overlays S[0]: freed at the iter-2 barrier; iter-3 reads S[1] only.
    int rr = tid >> 1, h = (tid & 1) * 16;
    unsigned int uu[8] = {stv0.x, stv0.y, stv0.z, stv0.w,
                          stv1.x, stv1.y, stv1.z, stv1.w};
#pragma unroll
    for (int j = 0; j < 8; ++j) {
      Vsw[rr * 32 + ((h + 2 * j + rr) & 31)] = (unsigned short)(uu[j] & 0xffff);
      Vsw[rr * 32 + ((h + 2 * j + 1 + rr) & 31)] = (unsigned short)(uu[j] >> 16);
    }
  }
  __syncthreads();  // full drain: TT vhi tiles landed; Vsw staged

  float ci2 = ws->inv_d4 * 1.44269504f;  // log2(e) folded into constants
  float local;
  if (is_ss) {
    if (bp == bq)
      local = epi_ss_st<0, true>(acc, ci2, tSq, tSlab, tSdv, Vsw, p0, q0, wr,
                                 wc, mrow, quad);
    else
      local = epi_ss_st<0, false>(acc, ci2, tSq, tSlab, tSdv, Vsw, p0, q0, wr,
                                  wc, mrow, quad);
  } else if (is_st) {
    local = epi_ss_st<1, false>(acc, ci2, tSq, tSlab, tSdv, Vsw, p0, q0, wr,
                                wc, mrow, quad);
  } else {
    if (bp == bq)
      local = epi_tt<true>(acc, ci2, tSq, SA, SB, p0, q0, wr, wc, mrow, quad);
    else
      local = epi_tt<false>(acc, ci2, tSq, SA, SB, p0, q0, wr, wc, mrow, quad);
  }

  double dl = (double)local;
#pragma unroll
  for (int off = 32; off; off >>= 1) dl += __shfl_down(dl, off, 64);
  if (lane == 0) red[w] = dl;  // red overlays S[1]: c3 reads done pre-barrier
  __syncthreads();
  if (tid == 0) ws->part[lin0] = red[0] + red[1] + red[2] + red[3];
#undef STAGE
}

__global__ __launch_bounds__(256) void k4_out(WS* __restrict__ ws,
                                              float* __restrict__ out) {
  __shared__ double sh[4];
  int tid = threadIdx.x, w = tid >> 6, lane = tid & 63;
  double s = 0.0;
  for (int i = tid; i < NBLK; i += 256) s += ws->part[i];
#pragma unroll
  for (int off = 32; off; off >>= 1) s += __shfl_down(s, off, 64);
  if (lane == 0) sh[w] = s;
  __syncthreads();
  if (tid == 0)
    out[0] = (float)((sh[0] + sh[1] + sh[2] + sh[3]) * (double)ws->inv_n_idx);
}

extern "C" void kernel_launch(void* const* d_in, const int* in_sizes, int n_in,
                              void* d_out, int out_size, void* d_ws, size_t ws_size,
                              hipStream_t stream) {
  const float* src = (const float*)d_in[0];
  const float* tgt = (const float*)d_in[1];
  const int* s_label = (const int*)d_in[2];
  const float* t_label = (const float*)d_in[3];
  float* out = (float*)d_out;
  WS* ws = (WS*)d_ws;  // ~4.3 MB

  kPrep<<<256, 256, 0, stream>>>(src, tgt, s_label, t_label, ws);
  kFin<<<32, 256, 0, stream>>>(t_label, ws);
  k3_main<<<NBLK, 256, 0, stream>>>(ws);
  k4_out<<<1, 256, 0, stream>>>(ws, out);
}

// Round 16
// 110.893 us; speedup vs baseline: 1.2149x; 1.2149x over previous
//
#include <hip/hip_runtime.h>
#include <cstddef>

// LMMD loss, round 29 = EXACT revert to round 27 (the 111.3-111.5 us best).
// r28's 2-buffer/(256,4) variant regressed +23 us: the 128-reg budget is
// UNIFIED VGPR+AGPR; 64 AGPR acc + 84 VGPR = 148 > 128 -> compiler clamped
// VGPR to 64 and spilled the epilogue (WRITE_SIZE 65 KB -> 44.6 MB, FETCH
// 6 -> 17 MB). 3 blocks/CU @ 170 regs is this kernel's occupancy optimum.
// All single-variable probes now exhausted (pipeline depth, LDS layouts,
// occupancy both directions, setprio, launch fusion, kPrep shapes, exp2).
// Config: atomic-free kPrep partials (256 blocks x 32 rows, batched xv[8]),
// kFin reduce, k3 3-buffer counted-vmcnt pipeline + fused TT weights + LDS
// epilogue tables + exp2 fold + T5 setprio, tiny k4_out. 4 dispatches.
// Budget: ~41 us harness poison fill (fixed) + ~38 us k3 (latency floor of
// this structure) + ~17 us small kernels + ~15 us launch gaps.
// loss = (1/n_idx) * sum_{p<=q} f_pq * w_pq * K(p,q),  f=2 off-diag, 1 diag
// Features: fp8 e4m3 MFMA (verified round 12: absmax 2.4e-4 < 4.9e-4).

#define B 4096
#define D 256
#define C 31
#define N2 8192
#define NTILE 64                       // 128-row tiles over 2B rows
#define NBLK (NTILE * (NTILE + 1) / 2) // 2080

typedef __attribute__((ext_vector_type(8))) short bf16x8;
typedef __attribute__((ext_vector_type(4))) float f32x4;

struct WS {
  float inv_n_idx;
  float inv_d4;
  float pSumsq[256];                  // per-block sum(x^2) partials
  unsigned pTpres[128];               // per-target-block argmax ballot mask
  alignas(16) float pMsum[256 * 256]; // [blk][col] column-sum partials
  alignas(16) int pScnt[128 * 32];    // [src blk][class] label counts
  alignas(16) float pTcnt[128 * 32];  // [tgt blk][class] t_label col sums
  float sq[N2];
  int slab[N2];
  float sdv[N2];
  alignas(16) unsigned char Thi8[(size_t)N2 * D];   // fp8 e4m3 (rotated)
  alignas(16) unsigned short vhi[(size_t)N2 * 32];  // bf16 v rows (tgt only)
  alignas(16) double part[NBLK];                    // per-block partial loss
};

static __device__ __forceinline__ unsigned short f2bf(float f) {
  unsigned int u = __float_as_uint(f);
  return (unsigned short)((u + 0x7fffu + ((u >> 16) & 1u)) >> 16);  // RNE
}
static __device__ __forceinline__ float bf2f(unsigned short s) {
  return __uint_as_float(((unsigned int)s) << 16);
}
static __device__ __forceinline__ float exp2_hw(float x) {
  float r;
  asm("v_exp_f32 %0, %1" : "=v"(r) : "v"(x));  // HW exp = 2^x
  return r;
}

#define GLD16(gsrc, ldst)                                                     \
  __builtin_amdgcn_global_load_lds(                                           \
      (const __attribute__((address_space(1))) void*)(gsrc),                  \
      (__attribute__((address_space(3))) void*)(ldst), 16, 0, 0)

// Prep + stats: fp8 feature pack, row sq, per-block partial stats.
// Blocks 0-127 cover source rows, 128-255 target rows (32 rows each).
__global__ __launch_bounds__(256) void kPrep(const float* __restrict__ src,
                                             const float* __restrict__ tgt,
                                             const int* __restrict__ s_label,
                                             const float* __restrict__ t_label,
                                             WS* __restrict__ ws) {
  int tid = threadIdx.x, w = tid >> 6, lane = tid & 63;
  int blk = blockIdx.x;
  int r0 = blk * 32;
  bool is_src = (r0 < B);  // whole block is one side (B % 32 == 0)
  __shared__ float rsq[32];
  __shared__ float colp[4][256];
  __shared__ int ls[32];
  __shared__ float lt[8][32];  // per-group partial class sums (target blocks)
  __shared__ int lpres[32];
  if (tid < 32) { ls[tid] = 0; lpres[tid] = 0; }

  const float* basep =
      is_src ? src + (size_t)r0 * D : tgt + (size_t)(r0 - B) * D;

  // ---- batched loads: 8 independent float4 loads in flight per thread ----
  float4 xv[8];
#pragma unroll
  for (int i = 0; i < 8; ++i)
    xv[i] = *(const float4*)(basep + (size_t)(w * 8 + i) * D + lane * 4);

  float ca0 = 0.f, ca1 = 0.f, ca2 = 0.f, ca3 = 0.f;
  // fp8 store position pieces: sub-row sc (64 B), granule gl (8 B), half hf
  int sc = lane >> 4, gl = (lane >> 1) & 7, hf = lane & 1;
#pragma unroll
  for (int i = 0; i < 8; ++i) {
    int rr = w * 8 + i;
    int p = r0 + rr;
    float4 x = xv[i];
    // fp8 e4m3 pack: byte0=x.x .. byte3=x.w (HW cvt)
    unsigned int pk = __builtin_amdgcn_cvt_pk_fp8_f32(x.x, x.y, 0, false);
    pk = __builtin_amdgcn_cvt_pk_fp8_f32(x.z, x.w, pk, true);
    // granule rotation keyed by row: r(p)=p+(p>>1) -> conflict-free b64
    // phases on the read side (all 32 banks hit once per 16-lane phase)
    int gp = (gl + p + (p >> 1)) & 7;
    *(unsigned int*)(&ws->Thi8[(size_t)p * D + sc * 64 + gp * 8 + hf * 4]) = pk;
    ca0 += x.x; ca1 += x.y; ca2 += x.z; ca3 += x.w;
    float s = x.x * x.x + x.y * x.y + x.z * x.z + x.w * x.w;
#pragma unroll
    for (int off = 32; off; off >>= 1) s += __shfl_down(s, off, 64);
    if (lane == 0) rsq[rr] = s;
  }
  colp[w][lane * 4 + 0] = ca0;
  colp[w][lane * 4 + 1] = ca1;
  colp[w][lane * 4 + 2] = ca2;
  colp[w][lane * 4 + 3] = ca3;

  // ---- target-block stats, parallel across all 256 threads ----
  if (!is_src) {
    // class sums: thread (g,c) sums rows {4g..4g+3} of class c
    int g = tid >> 5, c = tid & 31;
    float s = 0.f;
    if (c < C) {
#pragma unroll
      for (int k = 0; k < 4; ++k)
        s += t_label[(size_t)(r0 - B + g * 4 + k) * C + c];
    }
    lt[g][c] = s;
    // argmax: 8 threads per row, strided class scan, first-max combine
    int rr = tid >> 3, j = tid & 7;
    float best = -1e30f;
    int barg = 0;
    for (int c2 = j; c2 < C; c2 += 8) {
      float x = t_label[(size_t)(r0 - B + rr) * C + c2];
      if (x > best) { best = x; barg = c2; }  // in-thread scan is ascending
    }
#pragma unroll
    for (int m = 1; m < 8; m <<= 1) {
      float ob = __shfl_xor(best, m, 64);
      int oa = __shfl_xor(barg, m, 64);
      if (ob > best || (ob == best && oa < barg)) { best = ob; barg = oa; }
    }
    if (j == 0) lpres[barg] = 1;  // benign race (all writes are 1)
  }
  __syncthreads();

  if (tid < 32) {
    int p = r0 + tid;
    ws->sq[p] = rsq[tid];
    if (is_src) {
      int lb = s_label[p];
      ws->slab[p] = lb;
      atomicAdd(&ls[lb], 1);  // LDS atomic, 32 lanes, cheap
    } else {
      ws->slab[p] = 0;
    }
  }
  // block sum of sq -> per-block float partial (no global atomic)
  if (tid < 64) {
    float ss = (tid < 32) ? rsq[tid] : 0.f;
#pragma unroll
    for (int off = 32; off; off >>= 1) ss += __shfl_down(ss, off, 64);
    if (tid == 0) ws->pSumsq[blk] = ss;
  }
  // column-sum partials -> plain coalesced stores
  ws->pMsum[blk * 256 + tid] =
      colp[0][tid] + colp[1][tid] + colp[2][tid] + colp[3][tid];
  __syncthreads();
  if (is_src) {
    if (tid < 32) ws->pScnt[blk * 32 + tid] = ls[tid];
  } else {
    if (tid < 32) {
      float s = 0.f;
#pragma unroll
      for (int g = 0; g < 8; ++g) s += lt[g][tid];
      ws->pTcnt[(blk - 128) * 32 + tid] = s;
    }
    if (tid < 64) {  // ballot needs full wave 0
      int bit = (tid < 32) ? lpres[tid] : 0;
      unsigned long long bal = __ballot(bit != 0);
      if (tid == 0) ws->pTpres[blk - 128] = (unsigned)bal;
    }
  }
}

// Finalize: reduce partials -> divisors (redundant per block), inv_n_idx +
// inv_d4 (block 0), sdv all rows + vhi for target rows.
// 32 blocks x 256 threads = one row per thread.
__global__ __launch_bounds__(256) void kFin(const float* __restrict__ t_label,
                                            WS* __restrict__ ws) {
  int tid = threadIdx.x, w = tid >> 6, lane = tid & 63;
  __shared__ float sdiv[32], tdiv[32];
  __shared__ int rs[8][32];
  __shared__ float rt[8][32];
  __shared__ unsigned pm[2];
  __shared__ double dm[4], dsq[4];

  // class partials: thread (g,c) sums 16 blocks' entries
  {
    int g = tid >> 5, c = tid & 31;
    int cs = 0;
    float ts = 0.f;
#pragma unroll
    for (int k = 0; k < 16; ++k) {
      cs += ws->pScnt[(g * 16 + k) * 32 + c];
      ts += ws->pTcnt[(g * 16 + k) * 32 + c];
    }
    rs[g][c] = cs;
    rt[g][c] = ts;
  }
  // t_pres OR-reduce (128 masks, 2 waves)
  if (tid < 128) {
    unsigned m = ws->pTpres[tid];
#pragma unroll
    for (int off = 32; off; off >>= 1) m |= __shfl_down(m, off, 64);
    if ((tid & 63) == 0) pm[tid >> 6] = m;
  }
  __syncthreads();

  if (tid < 64) {
    int m = 0;
    if (tid < 32) {
      int cnt = 0;
      float t = 0.f;
#pragma unroll
      for (int g = 0; g < 8; ++g) { cnt += rs[g][tid]; t += rt[g][tid]; }
      unsigned pres = pm[0] | pm[1];
      m = (tid < C) && (cnt > 0) && ((pres >> tid) & 1u);
      sdiv[tid] = m ? 1.f / (float)cnt : 0.f;
      tdiv[tid] = m ? 1.f / ((t == 0.f) ? 100.f : t) : 0.f;
    }
    unsigned long long bal = __ballot(m);
    if (tid == 0 && blockIdx.x == 0)
      ws->inv_n_idx = 1.f / fmaxf((float)__popcll(bal), 1.f);
  }

  if (blockIdx.x == 0) {
    // Msum + sum_sq reduction -> inv_d4.
    double m = 0.0;
    for (int b2 = 0; b2 < 256; ++b2) m += (double)ws->pMsum[b2 * 256 + tid];
    double msq = m * m;
    double ssq = (double)ws->pSumsq[tid];
#pragma unroll
    for (int off = 32; off; off >>= 1) {
      msq += __shfl_down(msq, off, 64);
      ssq += __shfl_down(ssq, off, 64);
    }
    if (lane == 0) { dm[w] = msq; dsq[w] = ssq; }
    __syncthreads();
    if (tid == 0) {
      double MSQ = dm[0] + dm[1] + dm[2] + dm[3];
      double S = dsq[0] + dsq[1] + dsq[2] + dsq[3];
      double n = (double)N2;
      double sum_l2 = 2.0 * n * S - 2.0 * MSQ;
      double bw = sum_l2 / (n * n - n);
      bw = fmax(bw, 1e-6) * 0.25;  // / KERNEL_MUL^2
      ws->inv_d4 = (float)(1.0 / fmax(bw * 16.0, 1e-6));
    }
  }
  __syncthreads();

  int p = blockIdx.x * 256 + tid;
  if (p < B) {
    ws->sdv[p] = sdiv[ws->slab[p]];
  } else {
    ws->sdv[p] = 0.f;
    const float* r = t_label + (size_t)(p - B) * C;
    float vrow[32];
#pragma unroll
    for (int c = 0; c < 32; ++c) vrow[c] = (c < C) ? -r[c] * tdiv[c] : 0.f;
#pragma unroll
    for (int k = 0; k < 8; ++k) {
      ushort4 vh;
      vh.x = f2bf(vrow[k * 4 + 0]);
      vh.y = f2bf(vrow[k * 4 + 1]);
      vh.z = f2bf(vrow[k * 4 + 2]);
      vh.w = f2bf(vrow[k * 4 + 3]);
      *(ushort4*)(&ws->vhi[(size_t)p * 32 + k * 4]) = vh;
    }
  }
}

// ---- epilogue helpers (forceinlined; KIND 0=SS, 1=ST) ----
// Tables live in LDS: index p-side = local row, q-side = 128 + local row.
// ci2 = inv_d4 * log2(e): z is computed in log2 domain, y = 2^z (v_exp_f32).
template <int KIND, bool DIAG>
static __device__ __forceinline__ float epi_ss_st(
    const f32x4 (&acc)[4][4], float ci2, const float* tSq, const int* tSlab,
    const float* tSdv, const unsigned short* Vsw, int p0, int q0, int wr,
    int wc, int mrow, int quad) {
  float k2 = 2.f * ci2;
  float cq[4], sdq[4];
  int lq[4];
#pragma unroll
  for (int tj = 0; tj < 4; ++tj) {
    int iq = 128 + wc + tj * 16 + mrow;
    cq[tj] = -ci2 * tSq[iq];
    if (KIND == 0) {
      lq[tj] = tSlab[iq];
      sdq[tj] = tSdv[iq];
    }
  }
  float local = 0.f;
#pragma unroll
  for (int ti = 0; ti < 4; ++ti) {
#pragma unroll
    for (int rg = 0; rg < 4; ++rg) {
      int ip = wr + ti * 16 + quad * 4 + rg;
      float cpl = -ci2 * tSq[ip];
      int lp = tSlab[ip];
      float sp = tSdv[ip];
#pragma unroll
      for (int tj = 0; tj < 4; ++tj) {
        float z = fminf(fmaf(k2, acc[ti][tj][rg], cpl + cq[tj]), 0.f);
        float y = exp2_hw(z);
        float kv = y;
        y *= y; kv += y;
        y *= y; kv += y;
        y *= y; kv += y;
        y *= y; kv += y;
        float wv;
        if (KIND == 0) {
          wv = (lp == lq[tj]) ? sp * sdq[tj] : 0.f;
        } else {
          int ql = wc + tj * 16 + mrow;
          wv = sp * bf2f(Vsw[ql * 32 + ((lp + ql) & 31)]);
        }
        if (DIAG) {
          int p = p0 + ip;
          int q = q0 + wc + tj * 16 + mrow;
          float f = (q > p) ? 2.f : ((q == p) ? 1.f : 0.f);
          local = fmaf(wv * f, kv, local);
        } else {
          local = fmaf(wv, kv, local);
        }
      }
    }
  }
  if (!DIAG) local *= 2.f;
  return local;
}

// TT: weight fragment computed inline per (ti,tj) from staged vhi tiles.
template <bool DIAG>
static __device__ __forceinline__ float epi_tt(const f32x4 (&acc)[4][4],
                                               float ci2, const float* tSq,
                                               const unsigned short* SA,
                                               const unsigned short* SB,
                                               int p0, int q0, int wr, int wc,
                                               int mrow, int quad) {
  float k2 = 2.f * ci2;
  float cq[4];
#pragma unroll
  for (int tj = 0; tj < 4; ++tj)
    cq[tj] = -ci2 * tSq[128 + wc + tj * 16 + mrow];
  float cp[16];
#pragma unroll
  for (int ti = 0; ti < 4; ++ti)
#pragma unroll
    for (int rg = 0; rg < 4; ++rg)
      cp[ti * 4 + rg] = -ci2 * tSq[wr + ti * 16 + quad * 4 + rg];
  bf16x8 af[4], bfr[4];
#pragma unroll
  for (int ti = 0; ti < 4; ++ti)
    af[ti] = *(const bf16x8*)(SA + (wr + ti * 16 + mrow) * 32 + quad * 8);
#pragma unroll
  for (int tj = 0; tj < 4; ++tj)
    bfr[tj] = *(const bf16x8*)(SB + (wc + tj * 16 + mrow) * 32 + quad * 8);
  float local = 0.f;
#pragma unroll
  for (int ti = 0; ti < 4; ++ti) {
#pragma unroll
    for (int tj = 0; tj < 4; ++tj) {
      f32x4 wv4 = __builtin_amdgcn_mfma_f32_16x16x32_bf16(
          af[ti], bfr[tj], (f32x4){0.f, 0.f, 0.f, 0.f}, 0, 0, 0);
#pragma unroll
      for (int rg = 0; rg < 4; ++rg) {
        float z = fminf(fmaf(k2, acc[ti][tj][rg], cp[ti * 4 + rg] + cq[tj]), 0.f);
        float y = exp2_hw(z);
        float kv = y;
        y *= y; kv += y;
        y *= y; kv += y;
        y *= y; kv += y;
        y *= y; kv += y;
        if (DIAG) {
          int p = p0 + wr + ti * 16 + quad * 4 + rg;
          int q = q0 + wc + tj * 16 + mrow;
          float f = (q > p) ? 2.f : ((q == p) ? 1.f : 0.f);
          local = fmaf(wv4[rg] * f, kv, local);
        } else {
          local = fmaf(wv4[rg], kv, local);
        }
      }
    }
  }
  if (!DIAG) local *= 2.f;
  return local;
}

// One 64-B chunk = 2 t-steps x 16 fp8 MFMA from buffer fb (A) / fb+8192 (B).
// T5: the MFMA cluster runs at raised wave priority (neutral A/B r25; kept).
static __device__ __forceinline__ void do_chunk(const unsigned char* fb,
                                                f32x4 (&acc)[4][4],
                                                const int (&aAdr)[4],
                                                const int (&bAdr)[4]) {
#pragma unroll
  for (int t = 0; t < 2; ++t) {
    const int x = t << 5;
    long aF[4], bF[4];
#pragma unroll
    for (int ti = 0; ti < 4; ++ti)
      aF[ti] = *(const long*)(fb + (aAdr[ti] ^ x));
#pragma unroll
    for (int tj = 0; tj < 4; ++tj)
      bF[tj] = *(const long*)(fb + 8192 + (bAdr[tj] ^ x));
    __builtin_amdgcn_s_setprio(1);
#pragma unroll
    for (int ti = 0; ti < 4; ++ti)
#pragma unroll
      for (int tj = 0; tj < 4; ++tj)
        acc[ti][tj] = __builtin_amdgcn_mfma_f32_16x16x32_fp8_fp8(
            aF[ti], bF[tj], acc[ti][tj], 0, 0, 0);
    __builtin_amdgcn_s_setprio(0);
  }
}

// counted-vmcnt barrier: wait N outstanding VMEM, raw barrier, memory fence.
#define WBAR(N)                                                               \
  do {                                                                        \
    asm volatile("s_waitcnt vmcnt(" #N ")" ::: "memory");                     \
    __builtin_amdgcn_s_barrier();                                             \
    asm volatile("" ::: "memory");                                            \
  } while (0)

// Merged main kernel: fp8 features, conflict-free rotation, 3-buffer
// counted-vmcnt pipeline, fused TT weight GEMM, LDS epilogue tables.
__global__ __launch_bounds__(256, 3) void k3_main(WS* __restrict__ ws) {
  int tid = threadIdx.x, w = tid >> 6, lane = tid & 63;
  int lin0 = blockIdx.x;
  int e = (lin0 & 7) * (NBLK / 8) + (lin0 >> 3);
  int b = 0, nb = 484, rem = e;
  while (rem >= nb) { rem -= nb; ++b; nb -= 64; }
  int base = b * 8;
  int bq_, r;
  if (rem < 36) {  // triangular head of the band (bq within band)
    bq_ = 0;
    while ((bq_ + 1) * (bq_ + 2) / 2 <= rem) ++bq_;
    r = rem - (bq_ * (bq_ + 1)) / 2;
  } else {  // full-height 8-row columns
    int t = rem - 36;
    bq_ = 8 + (t >> 3);
    r = t & 7;
  }
  int bp = base + r, bq = base + bq_;
  int p0 = bp * 128, q0 = bq * 128;

  bool is_ss = (bq < 32);
  bool is_tt = (bp >= 32);
  bool is_st = !is_ss && !is_tt;

  // 3 staging buffers (48 KB) + 3 KB tables: chunk c -> buffer c%3.
  __shared__ __align__(16) unsigned char S[3][2][8192];
  __shared__ __align__(16) float tSq[256];
  __shared__ __align__(16) int tSlab[256];
  __shared__ __align__(16) float tSdv[256];
  // post-loop overlays: S[1] free after chunk-1 barrier, S[2] after chunk-2.
  unsigned short* Vsw = (unsigned short*)&S[1][0][0];  // ST weights
  unsigned short* SA = (unsigned short*)&S[1][0][0];   // TT vhi p-tile
  unsigned short* SB = (unsigned short*)&S[1][1][0];   // TT vhi q-tile
  double* red = (double*)&S[2][0][0];                  // wave partials

  const int wr = (w >> 1) * 64, wc = (w & 1) * 64;
  const int mrow = lane & 15, quad = lane >> 4;
  f32x4 acc[4][4];
#pragma unroll
  for (int i = 0; i < 4; ++i)
#pragma unroll
    for (int j = 0; j < 4; ++j) acc[i][j] = (f32x4){0.f, 0.f, 0.f, 0.f};

  const unsigned char* T8 = ws->Thi8;
  int rA = tid >> 2, cb16 = (tid & 3) * 16, cp8 = (tid & 3) * 8;
  const unsigned char* a_lo = T8 + (size_t)(p0 + rA) * D + cb16;
  const unsigned char* a_hi = a_lo + (size_t)64 * D;
  const unsigned char* b_lo = T8 + (size_t)(q0 + rA) * D + cb16;
  const unsigned char* b_hi = b_lo + (size_t)64 * D;

#define STAGE(bufi, off)                                                      \
  do {                                                                        \
    GLD16(a_lo + (off), &S[bufi][0][w * 1024]);                               \
    GLD16(a_hi + (off), &S[bufi][0][w * 1024 + 4096]);                        \
    GLD16(b_lo + (off), &S[bufi][1][w * 1024]);                               \
    GLD16(b_hi + (off), &S[bufi][1][w * 1024 + 4096]);                        \
  } while (0)

  // hoisted fragment byte-addresses (t=0); t=1 is ^32 (slot ^4)
  int aAdr[4], bAdr[4];
#pragma unroll
  for (int ti = 0; ti < 4; ++ti) {
    int Ra = wr + ti * 16 + mrow;
    aAdr[ti] = Ra * 64 + (((quad + Ra + (Ra >> 1)) & 7) << 3);
    int Rb = wc + ti * 16 + mrow;
    bAdr[ti] = Rb * 64 + (((quad + Rb + (Rb >> 1)) & 7) << 3);
  }

  uint4 stv0 = {0, 0, 0, 0}, stv1 = {0, 0, 0, 0};  // ST early-load regs

  // ---- prologue: c0, c1, tables (issue order fixes the vmcnt ladder) ----
  STAGE(0, 0);
  STAGE(1, 64);
  {
    // epilogue tables: 1024-B GLD16 each, lanes<32 = p-tile, >=32 = q-tile.
    // All 4 waves issue identical loads (same bytes -> benign race) so every
    // wave's outstanding-VMEM count is uniform for the counted waits below.
    int l32 = lane & 31;
    const float* s1 = ((lane < 32) ? ws->sq + p0 : ws->sq + q0) + l32 * 4;
    GLD16(s1, tSq);
    const int* s2 = ((lane < 32) ? ws->slab + p0 : ws->slab + q0) + l32 * 4;
    GLD16(s2, tSlab);
    const float* s3 = ((lane < 32) ? ws->sdv + p0 : ws->sdv + q0) + l32 * 4;
    GLD16(s3, tSdv);
  }
  WBAR(7);  // c0 resident (c1's 4 + tables' 3 still in flight)

  // ---- iter 0: compute c0, stage c2 ----
  STAGE(2, 128);
  do_chunk(&S[0][0][0], acc, aAdr, bAdr);
  WBAR(7);  // c1 resident (tables 3 + c2 4 in flight)

  // ---- iter 1: compute c1, stage c3 ----
  STAGE(0, 192);
  do_chunk(&S[1][0][0], acc, aAdr, bAdr);
  WBAR(4);  // c2 resident (tables retired in-order; c3 in flight)

  // ---- iter 2: compute c2; ST issues early vhi reg loads ----
  if (is_st) {
    const uint4* vsrc = (const uint4*)(ws->vhi + (size_t)(q0 + (tid >> 1)) * 32 +
                                       (tid & 1) * 16);
    stv0 = vsrc[0];
    stv1 = vsrc[1];
  }
  do_chunk(&S[2][0][0], acc, aAdr, bAdr);
  if (is_st) {
    WBAR(2);  // c3 resident; the 2 stv loads still in flight
  } else {
    WBAR(0);  // c3 resident
  }

  // ---- iter 3: compute c3; TT stages vhi tiles into S[1] ----
  if (is_tt) {
    const unsigned short* gA = ws->vhi + (size_t)(p0 + rA) * 32 + cp8;
    const unsigned short* gB = ws->vhi + (size_t)(q0 + rA) * 32 + cp8;
    GLD16(gA, &S[1][0][w * 1024]);
    GLD16(gA + (size_t)64 * 32, &S[1][0][w * 1024 + 4096]);
    GLD16(gB, &S[1][1][w * 1024]);
    GLD16(gB + (size_t)64 * 32, &S[1][1][w * 1024 + 4096]);
  }
  do_chunk(&S[0][0][0], acc, aAdr, bAdr);

  if (is_st) {
    // ST: write rotate-swizzled bf16 v rows from the early-loaded regs.
    // Vsw overlays S[1]: last read at chunk-1, two barriers ago.
    int rr = tid >> 1, h = (tid & 1) * 16;
    unsigned int uu[8] = {stv0.x, stv0.y, stv0.z, stv0.w,
                          stv1.x, stv1.y, stv1.z, stv1.w};
#pragma unroll
    for (int j = 0; j < 8; ++j) {
      Vsw[rr * 32 + ((h + 2 * j + rr) & 31)] = (unsigned short)(uu[j] & 0xffff);
      Vsw[rr * 32 + ((h + 2 * j + 1 + rr) & 31)] = (unsigned short)(uu[j] >> 16);
    }
  }
  __syncthreads();  // full drain: tables + TT tiles landed; Vsw staged

  float ci2 = ws->inv_d4 * 1.44269504f;  // log2(e) folded into constants
  float local;
  if (is_ss) {
    if (bp == bq)
      local = epi_ss_st<0, true>(acc, ci2, tSq, tSlab, tSdv, Vsw, p0, q0, wr,
                                 wc, mrow, quad);
    else
      local = epi_ss_st<0, false>(acc, ci2, tSq, tSlab, tSdv, Vsw, p0, q0, wr,
                                  wc, mrow, quad);
  } else if (is_st) {
    local = epi_ss_st<1, false>(acc, ci2, tSq, tSlab, tSdv, Vsw, p0, q0, wr,
                                wc, mrow, quad);
  } else {
    if (bp == bq)
      local = epi_tt<true>(acc, ci2, tSq, SA, SB, p0, q0, wr, wc, mrow, quad);
    else
      local = epi_tt<false>(acc, ci2, tSq, SA, SB, p0, q0, wr, wc, mrow, quad);
  }

  double dl = (double)local;
#pragma unroll
  for (int off = 32; off; off >>= 1) dl += __shfl_down(dl, off, 64);
  if (lane == 0) red[w] = dl;  // red overlays S[2]: feature reads long done
  __syncthreads();
  if (tid == 0) ws->part[lin0] = red[0] + red[1] + red[2] + red[3];
#undef STAGE
}

__global__ __launch_bounds__(256) void k4_out(WS* __restrict__ ws,
                                              float* __restrict__ out) {
  __shared__ double sh[4];
  int tid = threadIdx.x, w = tid >> 6, lane = tid & 63;
  double s = 0.0;
  for (int i = tid; i < NBLK; i += 256) s += ws->part[i];
#pragma unroll
  for (int off = 32; off; off >>= 1) s += __shfl_down(s, off, 64);
  if (lane == 0) sh[w] = s;
  __syncthreads();
  if (tid == 0)
    out[0] = (float)((sh[0] + sh[1] + sh[2] + sh[3]) * (double)ws->inv_n_idx);
}

extern "C" void kernel_launch(void* const* d_in, const int* in_sizes, int n_in,
                              void* d_out, int out_size, void* d_ws, size_t ws_size,
                              hipStream_t stream) {
  const float* src = (const float*)d_in[0];
  const float* tgt = (const float*)d_in[1];
  const int* s_label = (const int*)d_in[2];
  const float* t_label = (const float*)d_in[3];
  float* out = (float*)d_out;
  WS* ws = (WS*)d_ws;  // ~4.3 MB

  kPrep<<<256, 256, 0, stream>>>(src, tgt, s_label, t_label, ws);
  kFin<<<32, 256, 0, stream>>>(t_label, ws);
  k3_main<<<NBLK, 256, 0, stream>>>(ws);
  k4_out<<<1, 256, 0, stream>>>(ws, out);
}